// Round 7
// baseline (428.592 us; speedup 1.0000x reference)
//
#include <hip/hip_runtime.h>
#include <stdint.h>

typedef unsigned short u16;
typedef unsigned int u32;

#define S_LEN 4096
#define EMB 2048
#define NH 16
#define HD 128
#define HDTOT 2048
#define T_TILES 32
#define KANCH 8
#define SM_SCALE 0.088388347648318447f

typedef __bf16 bf16x8 __attribute__((ext_vector_type(8)));
typedef float f32x4 __attribute__((ext_vector_type(4)));

typedef const __attribute__((address_space(1))) u32 ga_u32;
typedef __attribute__((address_space(3))) u32 lds_u32;

__device__ __forceinline__ u16 f2bf(float f) {
  u32 b = __builtin_bit_cast(u32, f);
  b = (b + 0x7FFFu + ((b >> 16) & 1u)) >> 16;
  return (u16)b;
}
__device__ __forceinline__ float bf2f(u16 u) {
  return __builtin_bit_cast(float, ((u32)u) << 16);
}
__device__ __forceinline__ f32x4 mfma16(bf16x8 a, bf16x8 b, f32x4 c) {
  return __builtin_amdgcn_mfma_f32_16x16x32_bf16(a, b, c, 0, 0, 0);
}

#define ASM_LGKM0 do { asm volatile("s_waitcnt lgkmcnt(0)" ::: "memory"); \
                       __builtin_amdgcn_sched_barrier(0); } while (0)
#define ASM_VMC(n) do { asm volatile("s_waitcnt vmcnt(" #n ")" ::: "memory"); \
                        __builtin_amdgcn_sched_barrier(0); } while (0)

// -------- sincos table: ang[262144] -> float2 {cos,sin} (lives in d_out) ----
__global__ __launch_bounds__(256) void k_sincos(const float* __restrict__ ang,
                                                float2* __restrict__ tab) {
  int i = blockIdx.x * 256 + threadIdx.x;
  float a = ang[i];
  float s, c;
  __sincosf(a, &s, &c);
  tab[i] = make_float2(c, s);
}

// ---------------- x: fp32 -> bf16 ----------------
__global__ __launch_bounds__(256) void k_convert_x(const float* __restrict__ x,
                                                   u16* __restrict__ xb) {
  int i = (blockIdx.x * 256 + threadIdx.x) * 4;
  float4 v = *(const float4*)(x + i);
  ushort4 o;
  o.x = f2bf(v.x); o.y = f2bf(v.y); o.z = f2bf(v.z); o.w = f2bf(v.w);
  *(ushort4*)(xb + i) = o;
}

// ------- weights: [K=2048][N=2048] fp32 -> [N][K] bf16 (B^T for gemm) -------
__global__ __launch_bounds__(256) void k_transpose_w(
    const float* __restrict__ w0, const float* __restrict__ w1,
    const float* __restrict__ w2, const float* __restrict__ w3,
    u16* __restrict__ o0, u16* __restrict__ o1,
    u16* __restrict__ o2, u16* __restrict__ o3) {
  const float* w; u16* o;
  if (blockIdx.z == 0)      { w = w0; o = o0; }
  else if (blockIdx.z == 1) { w = w1; o = o1; }
  else if (blockIdx.z == 2) { w = w2; o = o2; }
  else                      { w = w3; o = o3; }
  __shared__ float tile[64][68];
  int n0 = blockIdx.x * 64, k0 = blockIdx.y * 64;
  int tid = threadIdx.x;
  int r = tid >> 4, cq = (tid & 15) << 2;
  for (int p = 0; p < 4; ++p) {
    float4 v = *(const float4*)(w + (size_t)(k0 + r + p * 16) * EMB + n0 + cq);
    tile[r + p * 16][cq + 0] = v.x;
    tile[r + p * 16][cq + 1] = v.y;
    tile[r + p * 16][cq + 2] = v.z;
    tile[r + p * 16][cq + 3] = v.w;
  }
  __syncthreads();
  for (int p = 0; p < 4; ++p) {
    int rn = r + p * 16;
    ushort4 u;
    u.x = f2bf(tile[cq + 0][rn]);
    u.y = f2bf(tile[cq + 1][rn]);
    u.z = f2bf(tile[cq + 2][rn]);
    u.w = f2bf(tile[cq + 3][rn]);
    *(ushort4*)(o + (size_t)(n0 + rn) * EMB + k0 + cq) = u;
  }
}

// ------- v: [S][HDTOT] bf16 -> vT [HDTOT][S] bf16 -------
__global__ __launch_bounds__(256) void k_transpose_v(const u16* __restrict__ v,
                                                     u16* __restrict__ vt) {
  __shared__ u16 tile[64][72];
  int n0 = blockIdx.x * 64, s0 = blockIdx.y * 64;
  int tid = threadIdx.x;
  int r = tid >> 4, cq = (tid & 15) << 2;
  for (int p = 0; p < 4; ++p) {
    ushort4 u = *(const ushort4*)(v + (size_t)(s0 + r + p * 16) * HDTOT + n0 + cq);
    tile[r + p * 16][cq + 0] = u.x;
    tile[r + p * 16][cq + 1] = u.y;
    tile[r + p * 16][cq + 2] = u.z;
    tile[r + p * 16][cq + 3] = u.w;
  }
  __syncthreads();
  for (int p = 0; p < 4; ++p) {
    int rn = r + p * 16;
    ushort4 o;
    o.x = tile[cq + 0][rn];
    o.y = tile[cq + 1][rn];
    o.z = tile[cq + 2][rn];
    o.w = tile[cq + 3][rn];
    *(ushort4*)(vt + (size_t)(n0 + rn) * S_LEN + s0 + cq) = o;
  }
}

// ------- m97-style bf16 GEMM core (128x128 tile, BK=32) — out-proj ---------
template <bool BF16OUT>
__device__ __forceinline__ void gemm_body(const u16* __restrict__ A,
                                          const u16* __restrict__ Bt,
                                          void* __restrict__ Cv,
                                          int N, int K, int m0, int n0,
                                          u16* As, u16* Bs) {
  const int tid = threadIdx.x;
  const int lane = tid & 63, wave = tid >> 6;
  const int quad = lane >> 4, l16 = lane & 15;
  const int wm = (wave >> 1) * 64, wn = (wave & 1) * 64;
  const int sw = (quad ^ (l16 & 3) ^ ((l16 >> 2) & 3)) * 8;  // u16 units
  f32x4 acc[4][4] = {};

  const int flat0 = wave * 1024 + lane * 16;  // byte offset within 8KB tile
  for (int kt = 0; kt < K; kt += 32) {
    for (int half = 0; half < 2; ++half) {
      int flat = flat0 + half * 4096;
      int row = flat >> 6;
      int gl = (flat >> 4) & 3;
      int colb = ((gl ^ (row & 3) ^ ((row >> 2) & 3)) << 4);  // pre-swizzled src
      const char* ga = (const char*)A + ((size_t)(m0 + row) * K + kt) * 2 + colb;
      const char* gb = (const char*)Bt + ((size_t)(n0 + row) * K + kt) * 2 + colb;
      int loff = wave * 1024 + half * 4096;  // wave-uniform LDS byte offset
      __builtin_amdgcn_global_load_lds((ga_u32*)ga, (lds_u32*)((char*)As + loff), 16, 0, 0);
      __builtin_amdgcn_global_load_lds((ga_u32*)gb, (lds_u32*)((char*)Bs + loff), 16, 0, 0);
    }
    __syncthreads();
    bf16x8 af[4], bfr[4];
    for (int mt = 0; mt < 4; ++mt)
      af[mt] = *(const bf16x8*)(As + (wm + mt * 16 + l16) * 32 + sw);
    for (int nt = 0; nt < 4; ++nt)
      bfr[nt] = *(const bf16x8*)(Bs + (wn + nt * 16 + l16) * 32 + sw);
    for (int mt = 0; mt < 4; ++mt)
      for (int nt = 0; nt < 4; ++nt)
        acc[mt][nt] = mfma16(af[mt], bfr[nt], acc[mt][nt]);
    __syncthreads();
  }
  for (int mt = 0; mt < 4; ++mt) {
    int row = m0 + wm + mt * 16 + quad * 4;
    for (int nt = 0; nt < 4; ++nt) {
      int col = n0 + wn + nt * 16 + l16;
      for (int r = 0; r < 4; ++r) {
        if (BF16OUT)
          ((u16*)Cv)[(size_t)(row + r) * N + col] = f2bf(acc[mt][nt][r]);
        else
          ((float*)Cv)[(size_t)(row + r) * N + col] = acc[mt][nt][r];
      }
    }
  }
}

template <bool BF16OUT>
__global__ __launch_bounds__(256) void k_gemm(const u16* __restrict__ A,
                                              const u16* __restrict__ Bt,
                                              void* __restrict__ Cv,
                                              int N, int K) {
  __shared__ __align__(16) u16 As[128 * 32];
  __shared__ __align__(16) u16 Bs[128 * 32];
  gemm_body<BF16OUT>(A, Bt, Cv, N, K, blockIdx.y * 128, blockIdx.x * 128, As, Bs);
}

// ======= 256x256 8-phase fused QKV GEMM + register-local RoPE ===============
// OBSERVABILITY SPLIT: launched twice with mb=0 / mb=8 (M-halves, 192 blocks
// each). Same total makespan as the fused 384-block launch (both are 2 rounds
// at 1 block/CU), but each dispatch is ~62us so other kernels can surface in
// the rocprof top-5 table.
__global__ __launch_bounds__(512, 2) void k_gemm256_qkv(
    const u16* __restrict__ A, const u16* __restrict__ Bt,
    u16* __restrict__ q, u16* __restrict__ k, u16* __restrict__ v,
    const float2* __restrict__ cssn, int mb) {
  __shared__ __align__(16) u16 lds[65536];
  int flat = blockIdx.y * 24 + blockIdx.x;
  flat = (flat & 7) * 24 + (flat >> 3);      // XCD-contiguous remap (192 = 8*24)
  const int bx = flat % 24, by = mb + flat / 24;
  const int m0 = by * 256;
  const int n0g = bx * 256;                  // row into concatenated [wqT;wkT;wvT]
  u16* out = (bx < 8) ? q : ((bx < 16) ? k : v);
  const int ncol0 = (bx & 7) * 256;

  const int tid = threadIdx.x;
  const int lane = tid & 63, wave = tid >> 6;
  const int quad = lane >> 4, l16 = lane & 15;
  const int wm = wave >> 2, wn = wave & 3;
  const int sw0 = (quad ^ (l16 & 7)) * 8, sw1 = ((quad ^ (l16 & 7)) ^ 4) * 8;

  // per-lane pre-swizzled global source offsets (LDS dest stays linear)
  size_t soff[2];
#pragma unroll
  for (int p = 0; p < 2; ++p) {
    int fl = p * 8192 + tid * 16;
    int row = fl >> 7;
    int gsw = ((fl >> 4) & 7) ^ (row & 7);
    soff[p] = (size_t)row * 4096 + (size_t)(gsw * 16);
  }
  const char* aBase = (const char*)A + (size_t)m0 * 4096;
  const char* bBase = (const char*)Bt + (size_t)n0g * 4096;
  const int dstW = wave * 1024;

  auto stA = [&](int buf, int half, int kt) {
#pragma unroll
    for (int p = 0; p < 2; ++p)
      __builtin_amdgcn_global_load_lds(
          (ga_u32*)(aBase + (size_t)half * 524288 + (size_t)kt * 128 + soff[p]),
          (lds_u32*)((char*)lds + buf * 32768 + half * 16384 + p * 8192 + dstW),
          16, 0, 0);
  };
  auto stB = [&](int buf, int half, int kt) {
#pragma unroll
    for (int p = 0; p < 2; ++p)
      __builtin_amdgcn_global_load_lds(
          (ga_u32*)(bBase + (size_t)half * 524288 + (size_t)kt * 128 + soff[p]),
          (lds_u32*)((char*)lds + 65536 + buf * 32768 + half * 16384 + p * 8192 + dstW),
          16, 0, 0);
  };
  // frag read bases (u16 units); B row = (wn + 4n)*16 + l16 -> + n*4096
  const u16* aRd = lds + wm * 8192 + l16 * 64;
  const u16* bRd = lds + 32768 + (wn * 16 + l16) * 64;

  f32x4 acc[8][4] = {};

  // prologue: tile0 fully + tile1 half0 (12 loads); drain tile0, keep 4 in flight
  stB(0, 0, 0); stA(0, 0, 0); stB(0, 1, 0); stA(0, 1, 0);
  stB(1, 0, 1); stA(1, 0, 1);
  ASM_VMC(4);
  __builtin_amdgcn_s_barrier();

  const int NT = EMB / 64;  // 32
  for (int j = 0; j < NT; ++j) {
    const int par = j & 1;
    const u16* aT = aRd + par * 16384;
    const u16* bT = bRd + par * 16384;
    bf16x8 af[4][2], blo[2][2], bhi[2][2];
    // ---- phase 1: C(0,0) quad — 12 ds_reads; stage (j+1).B1 ----
#pragma unroll
    for (int m = 0; m < 4; ++m) {
      af[m][0] = *(const bf16x8*)(aT + m * 1024 + sw0);
      af[m][1] = *(const bf16x8*)(aT + m * 1024 + sw1);
    }
#pragma unroll
    for (int n = 0; n < 2; ++n) {
      blo[n][0] = *(const bf16x8*)(bT + n * 4096 + sw0);
      blo[n][1] = *(const bf16x8*)(bT + n * 4096 + sw1);
    }
    if (j + 1 < NT) stB(1 - par, 1, j + 1);
    __builtin_amdgcn_s_barrier();
    ASM_LGKM0;
    __builtin_amdgcn_s_setprio(1);
#pragma unroll
    for (int m = 0; m < 4; ++m)
#pragma unroll
      for (int n = 0; n < 2; ++n) {
        acc[m][n] = mfma16(af[m][0], blo[n][0], acc[m][n]);
        acc[m][n] = mfma16(af[m][1], blo[n][1], acc[m][n]);
      }
    __builtin_amdgcn_s_setprio(0);
    __builtin_amdgcn_s_barrier();
    // ---- phase 2: C(0,1) quad — 4 ds_reads; stage (j+1).A1 ----
#pragma unroll
    for (int n = 0; n < 2; ++n) {
      bhi[n][0] = *(const bf16x8*)(bT + (n + 2) * 4096 + sw0);
      bhi[n][1] = *(const bf16x8*)(bT + (n + 2) * 4096 + sw1);
    }
    if (j + 1 < NT) stA(1 - par, 1, j + 1);
    __builtin_amdgcn_s_barrier();
    ASM_LGKM0;
    __builtin_amdgcn_s_setprio(1);
#pragma unroll
    for (int m = 0; m < 4; ++m)
#pragma unroll
      for (int n = 0; n < 2; ++n) {
        acc[m][n + 2] = mfma16(af[m][0], bhi[n][0], acc[m][n + 2]);
        acc[m][n + 2] = mfma16(af[m][1], bhi[n][1], acc[m][n + 2]);
      }
    __builtin_amdgcn_s_setprio(0);
    __builtin_amdgcn_s_barrier();
    // ---- phase 3: C(1,1) quad — 8 ds_reads; stage (j+2).B0 ----
#pragma unroll
    for (int m = 0; m < 4; ++m) {
      af[m][0] = *(const bf16x8*)(aT + (m + 4) * 1024 + sw0);
      af[m][1] = *(const bf16x8*)(aT + (m + 4) * 1024 + sw1);
    }
    if (j + 2 < NT) stB(par, 0, j + 2);
    __builtin_amdgcn_s_barrier();
    ASM_LGKM0;
    __builtin_amdgcn_s_setprio(1);
#pragma unroll
    for (int m = 0; m < 4; ++m)
#pragma unroll
      for (int n = 0; n < 2; ++n) {
        acc[m + 4][n + 2] = mfma16(af[m][0], bhi[n][0], acc[m + 4][n + 2]);
        acc[m + 4][n + 2] = mfma16(af[m][1], bhi[n][1], acc[m + 4][n + 2]);
      }
    __builtin_amdgcn_s_setprio(0);
    __builtin_amdgcn_s_barrier();
    // ---- phase 4: C(1,0) quad — stage (j+2).A0 ----
    if (j + 2 < NT) stA(par, 0, j + 2);
    __builtin_amdgcn_s_barrier();
    __builtin_amdgcn_s_setprio(1);
#pragma unroll
    for (int m = 0; m < 4; ++m)
#pragma unroll
      for (int n = 0; n < 2; ++n) {
        acc[m + 4][n] = mfma16(af[m][0], blo[n][0], acc[m + 4][n]);
        acc[m + 4][n] = mfma16(af[m][1], blo[n][1], acc[m + 4][n]);
      }
    __builtin_amdgcn_s_setprio(0);
    if (j == NT - 2) { ASM_VMC(0); } else { ASM_VMC(4); }  // drain tile j+1
    __builtin_amdgcn_s_barrier();
  }

  // ---- epilogue ----
  if (bx < 16) {
    // q/k: register-local RoPE. d = wn*16+l16 (same angle col for both heads)
    const int dcol = wn * 16 + l16;
#pragma unroll
    for (int m = 0; m < 8; ++m) {
      int srow = m0 + wm * 128 + m * 16 + quad * 4;
#pragma unroll
      for (int r = 0; r < 4; ++r) {
        int s = srow + r;
        float2 cs2 = cssn[s * 64 + dcol];
        u16* op = out + (size_t)s * HDTOT + ncol0 + dcol;
        float lo0 = acc[m][0][r], hi0 = acc[m][1][r];
        op[0]   = f2bf(lo0 * cs2.x - hi0 * cs2.y);
        op[64]  = f2bf(hi0 * cs2.x + lo0 * cs2.y);
        float lo1 = acc[m][2][r], hi1 = acc[m][3][r];
        op[128] = f2bf(lo1 * cs2.x - hi1 * cs2.y);
        op[192] = f2bf(hi1 * cs2.x + lo1 * cs2.y);
      }
    }
  } else {
    // v: plain store (note ntile = wn + 4n column mapping)
#pragma unroll
    for (int m = 0; m < 8; ++m) {
      int row = m0 + wm * 128 + m * 16 + quad * 4;
#pragma unroll
      for (int n = 0; n < 4; ++n) {
        int col = ncol0 + (wn + 4 * n) * 16 + l16;
#pragma unroll
        for (int r = 0; r < 4; ++r)
          out[(size_t)(row + r) * HDTOT + col] = f2bf(acc[m][n][r]);
      }
    }
  }
}

// ------- swizzled LDS fragment reads -------
__device__ __forceinline__ bf16x8 ldsfrag(const u16* __restrict__ sbuf, int r, int cb) {
  return *(const bf16x8*)(sbuf + r * 128 + (((cb ^ (r & 15)) << 3)));
}
__device__ __forceinline__ bf16x8 ldsfragV(const u16* __restrict__ sbuf, int r, int cb) {
  return *(const bf16x8*)(sbuf + r * 64 + (((cb ^ (r & 7)) << 3)));
}

// ------- block-sparse flash attention: one block per (t, h) ----------------
// (R6 structure, unchanged this round: 4 waves x 32 q-rows, shared K/V frags.)
__global__ __launch_bounds__(256, 2) void k_attn(const u16* __restrict__ q,
                                                 const u16* __restrict__ k,
                                                 const u16* __restrict__ vt,
                                                 const int* __restrict__ anch,
                                                 u16* __restrict__ out) {
  __shared__ __align__(16) u16 bufK[2][64 * 128];  // keys x dims (Q overlay at start)
  __shared__ __align__(16) u16 bufV[2][128 * 64];  // dims x keys
  __shared__ int s_tj[KANCH + 1];
  __shared__ int s_nv;
  const int i = blockIdx.x;
  const int p2 = (i ^ (i >> 8)) & 1;
  const int c = i >> 1;
  const int t = p2 ? (15 - (c >> 4)) : (16 + (c >> 4));
  const int h = c & 15;
  const int tid = threadIdx.x;
  const int lane = tid & 63, wave = tid >> 6;   // 4 waves
  const int quad = lane >> 4, l16 = lane & 15;
  const int wq0 = wave * 32;

  // K/V staging: 4 chunks/wave (K rows 0..63, V rows 0..127), swizzled cols
  int offK[4], offV[4];
#pragma unroll
  for (int p = 0; p < 4; ++p) {
    int krow = (wave * 4 + p) * 4 + (lane >> 4);
    int kcol = ((lane & 15) ^ (krow & 15)) << 3;
    offK[p] = (krow * HDTOT + kcol) * 2;
    int vrow = (wave * 4 + p) * 8 + (lane >> 3);
    int vcol = ((lane & 7) ^ (vrow & 7)) << 3;
    offV[p] = (vrow * S_LEN + vcol) * 2;
  }

  if (tid == 0) {
    int nv = 0;
    for (int j = 0; j < KANCH; ++j) {
      int tj = anch[((h * T_TILES) + t) * KANCH + j];
      if (tj <= t) s_tj[nv++] = tj;  // tj > t: fully future-masked, skip
    }
    s_tj[nv++] = t;  // local/diagonal tile
    s_nv = nv;
  }

  // stage full Q tile (128x128) into bufK[0]+bufK[1] (contiguous 32KB)
  {
    const char* gq = (const char*)(q + (size_t)(t * 128) * HDTOT + h * HD);
    char* lq = (char*)bufK + wave * 8192;
#pragma unroll
    for (int p = 0; p < 8; ++p) {
      int qrow = (wave * 8 + p) * 4 + (lane >> 4);
      int qcol = ((lane & 15) ^ (qrow & 15)) << 3;
      __builtin_amdgcn_global_load_lds((ga_u32*)(gq + (qrow * HDTOT + qcol) * 2),
                                       (lds_u32*)(lq + p * 1024), 16, 0, 0);
    }
  }
  __syncthreads();  // Q arrived; s_tj visible

  bf16x8 qf[2][4];  // Q B-frags: qrow = wq0 + qh*16 + l16
#pragma unroll
  for (int qh = 0; qh < 2; ++qh)
#pragma unroll
    for (int ks = 0; ks < 4; ++ks)
      qf[qh][ks] = ldsfrag(&bufK[0][0], wq0 + qh * 16 + l16, ks * 4 + quad);

  const int nv2 = 2 * s_nv;
  const char* kh = (const char*)(k + h * HD);
  const char* vh = (const char*)(vt + (size_t)(h * HD) * S_LEN);

  __syncthreads();  // all waves done reading Q before K0 DMA overwrites bufK[0]

  // issue half-tile 0 loads (drained at first loop barrier)
  {
    int key0 = s_tj[0] * 128;  // half 0
    const char* gk = kh + (size_t)key0 * (HDTOT * 2);
    const char* gv = vh + (size_t)key0 * 2;
    char* lk = (char*)bufK[0] + wave * 4096;
    char* lv = (char*)bufV[0] + wave * 4096;
#pragma unroll
    for (int p = 0; p < 4; ++p) {
      __builtin_amdgcn_global_load_lds((ga_u32*)(gk + offK[p]),
                                       (lds_u32*)(lk + p * 1024), 16, 0, 0);
      __builtin_amdgcn_global_load_lds((ga_u32*)(gv + offV[p]),
                                       (lds_u32*)(lv + p * 1024), 16, 0, 0);
    }
  }

  f32x4 oacc[2][8] = {};
  float m_st[2] = {-1e30f, -1e30f};
  float l_st[2] = {0.f, 0.f};

  for (int it = 0; it < nv2; ++it) {
    const int par = it & 1;
    const u16* K_c = bufK[par];
    const u16* V_c = bufV[par];
    const int tj = s_tj[it >> 1];
    const int half = it & 1;
    const bool diag = (tj == t);

    __syncthreads();  // drains half-tile-it loads; WAR-protects buffer 1-par

    // prefetch half-tile it+1 (in flight for the whole compute phase below)
    if (it + 1 < nv2) {
      int inx = it + 1;
      int key0 = s_tj[inx >> 1] * 128 + (inx & 1) * 64;
      const char* gk = kh + (size_t)key0 * (HDTOT * 2);
      const char* gv = vh + (size_t)key0 * 2;
      char* lk = (char*)bufK[1 - par] + wave * 4096;
      char* lv = (char*)bufV[1 - par] + wave * 4096;
#pragma unroll
      for (int p = 0; p < 4; ++p) {
        __builtin_amdgcn_global_load_lds((ga_u32*)(gk + offK[p]),
                                         (lds_u32*)(lk + p * 1024), 16, 0, 0);
        __builtin_amdgcn_global_load_lds((ga_u32*)(gv + offV[p]),
                                         (lds_u32*)(lv + p * 1024), 16, 0, 0);
      }
    }

    // S^T = K·Q^T : one kf read feeds both qh halves
    f32x4 sacc[2][4] = {};
    __builtin_amdgcn_s_setprio(1);
#pragma unroll
    for (int ks = 0; ks < 4; ++ks)
#pragma unroll
      for (int a = 0; a < 4; ++a) {
        bf16x8 kf = ldsfrag(K_c, a * 16 + l16, ks * 4 + quad);
        sacc[0][a] = mfma16(kf, qf[0][ks], sacc[0][a]);
        sacc[1][a] = mfma16(kf, qf[1][ks], sacc[1][a]);
      }
    __builtin_amdgcn_s_setprio(0);

    // online softmax per qh: lane holds 16 keys for qrow wq0+qh*16+l16
    u32 pl[2][4], ph[2][4];
    float alpha[2];
#pragma unroll
    for (int qh = 0; qh < 2; ++qh) {
      const int qr = wq0 + qh * 16 + l16;
      const int kb = half * 64;
      float rmax = -1e30f;
#pragma unroll
      for (int a = 0; a < 4; ++a) {
        f32x4 s4 = sacc[qh][a];
#pragma unroll
        for (int r = 0; r < 4; ++r) {
          float sv = s4[r] * SM_SCALE;
          if (diag && (kb + a * 16 + quad * 4 + r > qr)) sv = -1e30f;
          s4[r] = sv;
          rmax = fmaxf(rmax, sv);
        }
        sacc[qh][a] = s4;
      }
      rmax = fmaxf(rmax, __shfl_xor(rmax, 16));
      rmax = fmaxf(rmax, __shfl_xor(rmax, 32));
      float mnew = fmaxf(m_st[qh], rmax);
      alpha[qh] = __expf(m_st[qh] - mnew);
      m_st[qh] = mnew;
      float rsum = 0.f;
#pragma unroll
      for (int a = 0; a < 4; ++a) {
        f32x4 s4 = sacc[qh][a];
        float e0 = __expf(s4[0] - mnew);
        float e1 = __expf(s4[1] - mnew);
        float e2 = __expf(s4[2] - mnew);
        float e3 = __expf(s4[3] - mnew);
        rsum += (e0 + e1) + (e2 + e3);
        pl[qh][a] = __builtin_amdgcn_perm(__builtin_bit_cast(u32, e1) + 0x8000u,
                                          __builtin_bit_cast(u32, e0) + 0x8000u,
                                          0x07060302u);
        ph[qh][a] = __builtin_amdgcn_perm(__builtin_bit_cast(u32, e3) + 0x8000u,
                                          __builtin_bit_cast(u32, e2) + 0x8000u,
                                          0x07060302u);
      }
      rsum += __shfl_xor(rsum, 16);
      rsum += __shfl_xor(rsum, 32);
      l_st[qh] = l_st[qh] * alpha[qh] + rsum;
    }

    // rescale O (O rows are quad*4+r; alpha lives at lane l16 == row)
#pragma unroll
    for (int qh = 0; qh < 2; ++qh) {
      f32x4 av;
#pragma unroll
      for (int r = 0; r < 4; ++r)
        av[r] = __shfl(alpha[qh], (lane & 48) | (quad * 4 + r));
#pragma unroll
      for (int nt = 0; nt < 8; ++nt) {
        f32x4 o4 = oacc[qh][nt];
        o4[0] *= av[0]; o4[1] *= av[1]; o4[2] *= av[2]; o4[3] *= av[3];
        oacc[qh][nt] = o4;
      }
    }

    // O += P·V : A-frags via register shfl-transpose; one vf feeds both qh
    const int srcA = ((quad & 1) << 5) + l16;
    const int srcB = srcA + 16;
    const int hi = quad >> 1;
#pragma unroll
    for (int cc = 0; cc < 2; ++cc) {
      bf16x8 pa[2];
#pragma unroll
      for (int qh = 0; qh < 2; ++qh) {
        u32 x0 = __shfl(pl[qh][2 * cc], srcA), x1 = __shfl(ph[qh][2 * cc], srcA);
        u32 x2 = __shfl(pl[qh][2 * cc], srcB), x3 = __shfl(ph[qh][2 * cc], srcB);
        u32 y0 = __shfl(pl[qh][2 * cc + 1], srcA), y1 = __shfl(ph[qh][2 * cc + 1], srcA);
        u32 y2 = __shfl(pl[qh][2 * cc + 1], srcB), y3 = __shfl(ph[qh][2 * cc + 1], srcB);
        uint4 w;
        w.x = hi ? y0 : x0;
        w.y = hi ? y1 : x1;
        w.z = hi ? y2 : x2;
        w.w = hi ? y3 : x3;
        pa[qh] = __builtin_bit_cast(bf16x8, w);
      }
      __builtin_amdgcn_s_setprio(1);
#pragma unroll
      for (int nt = 0; nt < 8; ++nt) {
        bf16x8 vf = ldsfragV(V_c, nt * 16 + l16, cc * 4 + quad);
        oacc[0][nt] = mfma16(pa[0], vf, oacc[0][nt]);
        oacc[1][nt] = mfma16(pa[1], vf, oacc[1][nt]);
      }
      __builtin_amdgcn_s_setprio(0);
    }
  }

  // epilogue: normalize rows (1/l via shfl to O-row lanes) and store
#pragma unroll
  for (int qh = 0; qh < 2; ++qh) {
    float linv = 1.0f / l_st[qh];
    f32x4 iv;
#pragma unroll
    for (int r = 0; r < 4; ++r)
      iv[r] = __shfl(linv, (lane & 48) | (quad * 4 + r));
#pragma unroll
    for (int r = 0; r < 4; ++r) {
      size_t srow_o = (size_t)(t * 128 + wq0 + qh * 16 + quad * 4 + r);
#pragma unroll
      for (int nt = 0; nt < 8; ++nt)
        out[srow_o * HDTOT + h * HD + nt * 16 + l16] = f2bf(oacc[qh][nt][r] * iv[r]);
    }
  }
}

extern "C" void kernel_launch(void* const* d_in, const int* in_sizes, int n_in,
                              void* d_out, int out_size, void* d_ws, size_t ws_size,
                              hipStream_t stream) {
  const float* x   = (const float*)d_in[0];
  const float* wq  = (const float*)d_in[1];
  const float* wk  = (const float*)d_in[2];
  const float* wv  = (const float*)d_in[3];
  const float* wo  = (const float*)d_in[4];
  const float* ang = (const float*)d_in[5];
  const int* anch  = (const int*)d_in[6];

  char* ws = (char*)d_ws;
  const size_t SZ_SE = (size_t)S_LEN * HDTOT * sizeof(u16);  // 16 MB
  const size_t SZ_W  = (size_t)EMB * EMB * sizeof(u16);      // 8 MB
  u16* xb   = (u16*)(ws);
  u16* qb   = (u16*)(ws + SZ_SE);
  u16* kb   = (u16*)(ws + 2 * SZ_SE);
  u16* vb   = (u16*)(ws + 3 * SZ_SE);
  u16* vtb  = (u16*)(ws + 4 * SZ_SE);
  u16* attn = (u16*)(ws + 5 * SZ_SE);
  u16* wqT  = (u16*)(ws + 6 * SZ_SE);            // wqT,wkT,wvT contiguous ->
  u16* wkT  = (u16*)(ws + 6 * SZ_SE + SZ_W);     // single B^T for fused QKV
  u16* wvT  = (u16*)(ws + 6 * SZ_SE + 2 * SZ_W);
  u16* woT  = (u16*)(ws + 6 * SZ_SE + 3 * SZ_W);

  // cos/sin table lives in the first 2MB of d_out (overwritten by final gemm)
  float2* cssn = (float2*)d_out;

  k_sincos<<<1024, 256, 0, stream>>>(ang, cssn);
  k_convert_x<<<8192, 256, 0, stream>>>(x, xb);
  k_transpose_w<<<dim3(32, 32, 4), 256, 0, stream>>>(wq, wk, wv, wo, wqT, wkT, wvT, woT);
  k_gemm256_qkv<<<dim3(24, 8), 512, 0, stream>>>(xb, wqT, qb, kb, vb, cssn, 0);
  k_gemm256_qkv<<<dim3(24, 8), 512, 0, stream>>>(xb, wqT, qb, kb, vb, cssn, 8);
  k_transpose_v<<<dim3(32, 64), 256, 0, stream>>>(vb, vtb);
  k_attn<<<dim3(512), 256, 0, stream>>>(qb, kb, vtb, anch, attn);
  // out-proj split into two M-halves (observability; pointer offsets only)
  k_gemm<false><<<dim3(16, 16), 256, 0, stream>>>(attn, woT, d_out, EMB, HDTOT);
  k_gemm<false><<<dim3(16, 16), 256, 0, stream>>>(attn + (size_t)2048 * HDTOT, woT,
                                                  (float*)d_out + (size_t)2048 * EMB,
                                                  EMB, HDTOT);
}

// Round 8
// 384.387 us; speedup vs baseline: 1.1150x; 1.1150x over previous
//
#include <hip/hip_runtime.h>
#include <stdint.h>

typedef unsigned short u16;
typedef unsigned int u32;

#define S_LEN 4096
#define EMB 2048
#define NH 16
#define HD 128
#define HDTOT 2048
#define T_TILES 32
#define KANCH 8
#define SM_SCALE 0.088388347648318447f

typedef __bf16 bf16x8 __attribute__((ext_vector_type(8)));
typedef float f32x4 __attribute__((ext_vector_type(4)));

typedef const __attribute__((address_space(1))) u32 ga_u32;
typedef __attribute__((address_space(3))) u32 lds_u32;

__device__ __forceinline__ u16 f2bf(float f) {
  u32 b = __builtin_bit_cast(u32, f);
  b = (b + 0x7FFFu + ((b >> 16) & 1u)) >> 16;
  return (u16)b;
}
__device__ __forceinline__ float bf2f(u16 u) {
  return __builtin_bit_cast(float, ((u32)u) << 16);
}
__device__ __forceinline__ f32x4 mfma16(bf16x8 a, bf16x8 b, f32x4 c) {
  return __builtin_amdgcn_mfma_f32_16x16x32_bf16(a, b, c, 0, 0, 0);
}

#define ASM_LGKM0 do { asm volatile("s_waitcnt lgkmcnt(0)" ::: "memory"); \
                       __builtin_amdgcn_sched_barrier(0); } while (0)
#define ASM_VMC(n) do { asm volatile("s_waitcnt vmcnt(" #n ")" ::: "memory"); \
                        __builtin_amdgcn_sched_barrier(0); } while (0)

// ======= fused prep: convert_x (8192 blk) + transpose_w (4096) + sincos =====
// Launch-count consolidation: 3 independent preprocessing kernels -> 1.
__global__ __launch_bounds__(256) void k_prep(
    const float* __restrict__ x, u16* __restrict__ xb,
    const float* __restrict__ w0, const float* __restrict__ w1,
    const float* __restrict__ w2, const float* __restrict__ w3,
    u16* __restrict__ o0, u16* __restrict__ o1,
    u16* __restrict__ o2, u16* __restrict__ o3,
    const float* __restrict__ ang, float2* __restrict__ tab) {
  __shared__ float tile[64][68];
  const int bid = blockIdx.x;
  const int tid = threadIdx.x;
  if (bid < 8192) {
    // ---- x: fp32 -> bf16 ----
    int i = (bid * 256 + tid) * 4;
    float4 v = *(const float4*)(x + i);
    ushort4 o;
    o.x = f2bf(v.x); o.y = f2bf(v.y); o.z = f2bf(v.z); o.w = f2bf(v.w);
    *(ushort4*)(xb + i) = o;
  } else if (bid < 12288) {
    // ---- weights [K][N] fp32 -> [N][K] bf16 ----
    int idx = bid - 8192;
    int z = idx >> 10, rem = idx & 1023;
    int n0 = (rem & 31) * 64, k0 = (rem >> 5) * 64;
    const float* w; u16* o;
    if (z == 0)      { w = w0; o = o0; }
    else if (z == 1) { w = w1; o = o1; }
    else if (z == 2) { w = w2; o = o2; }
    else             { w = w3; o = o3; }
    int r = tid >> 4, cq = (tid & 15) << 2;
    for (int p = 0; p < 4; ++p) {
      float4 v = *(const float4*)(w + (size_t)(k0 + r + p * 16) * EMB + n0 + cq);
      tile[r + p * 16][cq + 0] = v.x;
      tile[r + p * 16][cq + 1] = v.y;
      tile[r + p * 16][cq + 2] = v.z;
      tile[r + p * 16][cq + 3] = v.w;
    }
    __syncthreads();
    for (int p = 0; p < 4; ++p) {
      int rn = r + p * 16;
      ushort4 u;
      u.x = f2bf(tile[cq + 0][rn]);
      u.y = f2bf(tile[cq + 1][rn]);
      u.z = f2bf(tile[cq + 2][rn]);
      u.w = f2bf(tile[cq + 3][rn]);
      *(ushort4*)(o + (size_t)(n0 + rn) * EMB + k0 + cq) = u;
    }
  } else {
    // ---- sincos table ----
    int i = (bid - 12288) * 256 + tid;
    float a = ang[i];
    float s, c;
    __sincosf(a, &s, &c);
    tab[i] = make_float2(c, s);
  }
}

// ------- v: [S][HDTOT] bf16 -> vT [HDTOT][S] bf16 -------
__global__ __launch_bounds__(256) void k_transpose_v(const u16* __restrict__ v,
                                                     u16* __restrict__ vt) {
  __shared__ u16 tile[64][72];
  int n0 = blockIdx.x * 64, s0 = blockIdx.y * 64;
  int tid = threadIdx.x;
  int r = tid >> 4, cq = (tid & 15) << 2;
  for (int p = 0; p < 4; ++p) {
    ushort4 u = *(const ushort4*)(v + (size_t)(s0 + r + p * 16) * HDTOT + n0 + cq);
    tile[r + p * 16][cq + 0] = u.x;
    tile[r + p * 16][cq + 1] = u.y;
    tile[r + p * 16][cq + 2] = u.z;
    tile[r + p * 16][cq + 3] = u.w;
  }
  __syncthreads();
  for (int p = 0; p < 4; ++p) {
    int rn = r + p * 16;
    ushort4 o;
    o.x = tile[cq + 0][rn];
    o.y = tile[cq + 1][rn];
    o.z = tile[cq + 2][rn];
    o.w = tile[cq + 3][rn];
    *(ushort4*)(vt + (size_t)(n0 + rn) * S_LEN + s0 + cq) = o;
  }
}

// ------- m97-style bf16 GEMM core (128x128 tile, BK=32) — out-proj ---------
template <bool BF16OUT>
__device__ __forceinline__ void gemm_body(const u16* __restrict__ A,
                                          const u16* __restrict__ Bt,
                                          void* __restrict__ Cv,
                                          int N, int K, int m0, int n0,
                                          u16* As, u16* Bs) {
  const int tid = threadIdx.x;
  const int lane = tid & 63, wave = tid >> 6;
  const int quad = lane >> 4, l16 = lane & 15;
  const int wm = (wave >> 1) * 64, wn = (wave & 1) * 64;
  const int sw = (quad ^ (l16 & 3) ^ ((l16 >> 2) & 3)) * 8;  // u16 units
  f32x4 acc[4][4] = {};

  const int flat0 = wave * 1024 + lane * 16;  // byte offset within 8KB tile
  for (int kt = 0; kt < K; kt += 32) {
    for (int half = 0; half < 2; ++half) {
      int flat = flat0 + half * 4096;
      int row = flat >> 6;
      int gl = (flat >> 4) & 3;
      int colb = ((gl ^ (row & 3) ^ ((row >> 2) & 3)) << 4);  // pre-swizzled src
      const char* ga = (const char*)A + ((size_t)(m0 + row) * K + kt) * 2 + colb;
      const char* gb = (const char*)Bt + ((size_t)(n0 + row) * K + kt) * 2 + colb;
      int loff = wave * 1024 + half * 4096;  // wave-uniform LDS byte offset
      __builtin_amdgcn_global_load_lds((ga_u32*)ga, (lds_u32*)((char*)As + loff), 16, 0, 0);
      __builtin_amdgcn_global_load_lds((ga_u32*)gb, (lds_u32*)((char*)Bs + loff), 16, 0, 0);
    }
    __syncthreads();
    bf16x8 af[4], bfr[4];
    for (int mt = 0; mt < 4; ++mt)
      af[mt] = *(const bf16x8*)(As + (wm + mt * 16 + l16) * 32 + sw);
    for (int nt = 0; nt < 4; ++nt)
      bfr[nt] = *(const bf16x8*)(Bs + (wn + nt * 16 + l16) * 32 + sw);
    for (int mt = 0; mt < 4; ++mt)
      for (int nt = 0; nt < 4; ++nt)
        acc[mt][nt] = mfma16(af[mt], bfr[nt], acc[mt][nt]);
    __syncthreads();
  }
  for (int mt = 0; mt < 4; ++mt) {
    int row = m0 + wm + mt * 16 + quad * 4;
    for (int nt = 0; nt < 4; ++nt) {
      int col = n0 + wn + nt * 16 + l16;
      for (int r = 0; r < 4; ++r) {
        if (BF16OUT)
          ((u16*)Cv)[(size_t)(row + r) * N + col] = f2bf(acc[mt][nt][r]);
        else
          ((float*)Cv)[(size_t)(row + r) * N + col] = acc[mt][nt][r];
      }
    }
  }
}

template <bool BF16OUT>
__global__ __launch_bounds__(256) void k_gemm(const u16* __restrict__ A,
                                              const u16* __restrict__ Bt,
                                              void* __restrict__ Cv,
                                              int N, int K) {
  __shared__ __align__(16) u16 As[128 * 32];
  __shared__ __align__(16) u16 Bs[128 * 32];
  gemm_body<BF16OUT>(A, Bt, Cv, N, K, blockIdx.y * 128, blockIdx.x * 128, As, Bs);
}

// ======= 256x256 8-phase fused QKV GEMM + register-local RoPE (R6 cfg) ======
__global__ __launch_bounds__(512, 2) void k_gemm256_qkv(
    const u16* __restrict__ A, const u16* __restrict__ Bt,
    u16* __restrict__ q, u16* __restrict__ k, u16* __restrict__ v,
    const float2* __restrict__ cssn) {
  __shared__ __align__(16) u16 lds[65536];
  int flat = blockIdx.y * 24 + blockIdx.x;
  flat = (flat & 7) * 48 + (flat >> 3);      // XCD-contiguous remap (384 = 8*48)
  const int bx = flat % 24, by = flat / 24;
  const int m0 = by * 256;
  const int n0g = bx * 256;                  // row into concatenated [wqT;wkT;wvT]
  u16* out = (bx < 8) ? q : ((bx < 16) ? k : v);
  const int ncol0 = (bx & 7) * 256;

  const int tid = threadIdx.x;
  const int lane = tid & 63, wave = tid >> 6;
  const int quad = lane >> 4, l16 = lane & 15;
  const int wm = wave >> 2, wn = wave & 3;
  const int sw0 = (quad ^ (l16 & 7)) * 8, sw1 = ((quad ^ (l16 & 7)) ^ 4) * 8;

  // per-lane pre-swizzled global source offsets (LDS dest stays linear)
  size_t soff[2];
#pragma unroll
  for (int p = 0; p < 2; ++p) {
    int fl = p * 8192 + tid * 16;
    int row = fl >> 7;
    int gsw = ((fl >> 4) & 7) ^ (row & 7);
    soff[p] = (size_t)row * 4096 + (size_t)(gsw * 16);
  }
  const char* aBase = (const char*)A + (size_t)m0 * 4096;
  const char* bBase = (const char*)Bt + (size_t)n0g * 4096;
  const int dstW = wave * 1024;

  auto stA = [&](int buf, int half, int kt) {
#pragma unroll
    for (int p = 0; p < 2; ++p)
      __builtin_amdgcn_global_load_lds(
          (ga_u32*)(aBase + (size_t)half * 524288 + (size_t)kt * 128 + soff[p]),
          (lds_u32*)((char*)lds + buf * 32768 + half * 16384 + p * 8192 + dstW),
          16, 0, 0);
  };
  auto stB = [&](int buf, int half, int kt) {
#pragma unroll
    for (int p = 0; p < 2; ++p)
      __builtin_amdgcn_global_load_lds(
          (ga_u32*)(bBase + (size_t)half * 524288 + (size_t)kt * 128 + soff[p]),
          (lds_u32*)((char*)lds + 65536 + buf * 32768 + half * 16384 + p * 8192 + dstW),
          16, 0, 0);
  };
  // frag read bases (u16 units); B row = (wn + 4n)*16 + l16 -> + n*4096
  const u16* aRd = lds + wm * 8192 + l16 * 64;
  const u16* bRd = lds + 32768 + (wn * 16 + l16) * 64;

  f32x4 acc[8][4] = {};

  // prologue: tile0 fully + tile1 half0 (12 loads); drain tile0, keep 4 in flight
  stB(0, 0, 0); stA(0, 0, 0); stB(0, 1, 0); stA(0, 1, 0);
  stB(1, 0, 1); stA(1, 0, 1);
  ASM_VMC(4);
  __builtin_amdgcn_s_barrier();

  const int NT = EMB / 64;  // 32
  for (int j = 0; j < NT; ++j) {
    const int par = j & 1;
    const u16* aT = aRd + par * 16384;
    const u16* bT = bRd + par * 16384;
    bf16x8 af[4][2], blo[2][2], bhi[2][2];
    // ---- phase 1: C(0,0) quad — 12 ds_reads; stage (j+1).B1 ----
#pragma unroll
    for (int m = 0; m < 4; ++m) {
      af[m][0] = *(const bf16x8*)(aT + m * 1024 + sw0);
      af[m][1] = *(const bf16x8*)(aT + m * 1024 + sw1);
    }
#pragma unroll
    for (int n = 0; n < 2; ++n) {
      blo[n][0] = *(const bf16x8*)(bT + n * 4096 + sw0);
      blo[n][1] = *(const bf16x8*)(bT + n * 4096 + sw1);
    }
    if (j + 1 < NT) stB(1 - par, 1, j + 1);
    __builtin_amdgcn_s_barrier();
    ASM_LGKM0;
    __builtin_amdgcn_s_setprio(1);
#pragma unroll
    for (int m = 0; m < 4; ++m)
#pragma unroll
      for (int n = 0; n < 2; ++n) {
        acc[m][n] = mfma16(af[m][0], blo[n][0], acc[m][n]);
        acc[m][n] = mfma16(af[m][1], blo[n][1], acc[m][n]);
      }
    __builtin_amdgcn_s_setprio(0);
    __builtin_amdgcn_s_barrier();
    // ---- phase 2: C(0,1) quad — 4 ds_reads; stage (j+1).A1 ----
#pragma unroll
    for (int n = 0; n < 2; ++n) {
      bhi[n][0] = *(const bf16x8*)(bT + (n + 2) * 4096 + sw0);
      bhi[n][1] = *(const bf16x8*)(bT + (n + 2) * 4096 + sw1);
    }
    if (j + 1 < NT) stA(1 - par, 1, j + 1);
    __builtin_amdgcn_s_barrier();
    ASM_LGKM0;
    __builtin_amdgcn_s_setprio(1);
#pragma unroll
    for (int m = 0; m < 4; ++m)
#pragma unroll
      for (int n = 0; n < 2; ++n) {
        acc[m][n + 2] = mfma16(af[m][0], bhi[n][0], acc[m][n + 2]);
        acc[m][n + 2] = mfma16(af[m][1], bhi[n][1], acc[m][n + 2]);
      }
    __builtin_amdgcn_s_setprio(0);
    __builtin_amdgcn_s_barrier();
    // ---- phase 3: C(1,1) quad — 8 ds_reads; stage (j+2).B0 ----
#pragma unroll
    for (int m = 0; m < 4; ++m) {
      af[m][0] = *(const bf16x8*)(aT + (m + 4) * 1024 + sw0);
      af[m][1] = *(const bf16x8*)(aT + (m + 4) * 1024 + sw1);
    }
    if (j + 2 < NT) stB(par, 0, j + 2);
    __builtin_amdgcn_s_barrier();
    ASM_LGKM0;
    __builtin_amdgcn_s_setprio(1);
#pragma unroll
    for (int m = 0; m < 4; ++m)
#pragma unroll
      for (int n = 0; n < 2; ++n) {
        acc[m + 4][n + 2] = mfma16(af[m][0], bhi[n][0], acc[m + 4][n + 2]);
        acc[m + 4][n + 2] = mfma16(af[m][1], bhi[n][1], acc[m + 4][n + 2]);
      }
    __builtin_amdgcn_s_setprio(0);
    __builtin_amdgcn_s_barrier();
    // ---- phase 4: C(1,0) quad — stage (j+2).A0 ----
    if (j + 2 < NT) stA(par, 0, j + 2);
    __builtin_amdgcn_s_barrier();
    __builtin_amdgcn_s_setprio(1);
#pragma unroll
    for (int m = 0; m < 4; ++m)
#pragma unroll
      for (int n = 0; n < 2; ++n) {
        acc[m + 4][n] = mfma16(af[m][0], blo[n][0], acc[m + 4][n]);
        acc[m + 4][n] = mfma16(af[m][1], blo[n][1], acc[m + 4][n]);
      }
    __builtin_amdgcn_s_setprio(0);
    if (j == NT - 2) { ASM_VMC(0); } else { ASM_VMC(4); }  // drain tile j+1
    __builtin_amdgcn_s_barrier();
  }

  // ---- epilogue ----
  if (bx < 16) {
    // q/k: register-local RoPE. d = wn*16+l16 (same angle col for both heads)
    const int dcol = wn * 16 + l16;
#pragma unroll
    for (int m = 0; m < 8; ++m) {
      int srow = m0 + wm * 128 + m * 16 + quad * 4;
#pragma unroll
      for (int r = 0; r < 4; ++r) {
        int s = srow + r;
        float2 cs2 = cssn[s * 64 + dcol];
        u16* op = out + (size_t)s * HDTOT + ncol0 + dcol;
        float lo0 = acc[m][0][r], hi0 = acc[m][1][r];
        op[0]   = f2bf(lo0 * cs2.x - hi0 * cs2.y);
        op[64]  = f2bf(hi0 * cs2.x + lo0 * cs2.y);
        float lo1 = acc[m][2][r], hi1 = acc[m][3][r];
        op[128] = f2bf(lo1 * cs2.x - hi1 * cs2.y);
        op[192] = f2bf(hi1 * cs2.x + lo1 * cs2.y);
      }
    }
  } else {
    // v: plain store (note ntile = wn + 4n column mapping)
#pragma unroll
    for (int m = 0; m < 8; ++m) {
      int row = m0 + wm * 128 + m * 16 + quad * 4;
#pragma unroll
      for (int n = 0; n < 4; ++n) {
        int col = ncol0 + (wn + 4 * n) * 16 + l16;
#pragma unroll
        for (int r = 0; r < 4; ++r)
          out[(size_t)(row + r) * HDTOT + col] = f2bf(acc[m][n][r]);
      }
    }
  }
}

// ------- swizzled LDS fragment reads -------
__device__ __forceinline__ bf16x8 ldsfrag(const u16* __restrict__ sbuf, int r, int cb) {
  return *(const bf16x8*)(sbuf + r * 128 + (((cb ^ (r & 15)) << 3)));
}
__device__ __forceinline__ bf16x8 ldsfragV(const u16* __restrict__ sbuf, int r, int cb) {
  return *(const bf16x8*)(sbuf + r * 64 + (((cb ^ (r & 7)) << 3)));
}

// ------- block-sparse flash attention: one block per (t, h) ----------------
// R6 structure + exact defer-max (skip rescale when no lane's max grew — no
// threshold, mathematically exact) + tree-shaped max reduction to shorten the
// latency-bound serial chain identified by R7's counters (Mfma 11%, VALU 24%,
// occ 12% — nothing busy => per-iter critical path dominates).
__global__ __launch_bounds__(256, 2) void k_attn(const u16* __restrict__ q,
                                                 const u16* __restrict__ k,
                                                 const u16* __restrict__ vt,
                                                 const int* __restrict__ anch,
                                                 u16* __restrict__ out) {
  __shared__ __align__(16) u16 bufK[2][64 * 128];  // keys x dims (Q overlay at start)
  __shared__ __align__(16) u16 bufV[2][128 * 64];  // dims x keys
  __shared__ int s_tj[KANCH + 1];
  __shared__ int s_nv;
  const int i = blockIdx.x;
  const int p2 = (i ^ (i >> 8)) & 1;
  const int c = i >> 1;
  const int t = p2 ? (15 - (c >> 4)) : (16 + (c >> 4));
  const int h = c & 15;
  const int tid = threadIdx.x;
  const int lane = tid & 63, wave = tid >> 6;   // 4 waves
  const int quad = lane >> 4, l16 = lane & 15;
  const int wq0 = wave * 32;

  // K/V staging: 4 chunks/wave (K rows 0..63, V rows 0..127), swizzled cols
  int offK[4], offV[4];
#pragma unroll
  for (int p = 0; p < 4; ++p) {
    int krow = (wave * 4 + p) * 4 + (lane >> 4);
    int kcol = ((lane & 15) ^ (krow & 15)) << 3;
    offK[p] = (krow * HDTOT + kcol) * 2;
    int vrow = (wave * 4 + p) * 8 + (lane >> 3);
    int vcol = ((lane & 7) ^ (vrow & 7)) << 3;
    offV[p] = (vrow * S_LEN + vcol) * 2;
  }

  if (tid == 0) {
    int nv = 0;
    for (int j = 0; j < KANCH; ++j) {
      int tj = anch[((h * T_TILES) + t) * KANCH + j];
      if (tj <= t) s_tj[nv++] = tj;  // tj > t: fully future-masked, skip
    }
    s_tj[nv++] = t;  // local/diagonal tile
    s_nv = nv;
  }

  // stage full Q tile (128x128) into bufK[0]+bufK[1] (contiguous 32KB)
  {
    const char* gq = (const char*)(q + (size_t)(t * 128) * HDTOT + h * HD);
    char* lq = (char*)bufK + wave * 8192;
#pragma unroll
    for (int p = 0; p < 8; ++p) {
      int qrow = (wave * 8 + p) * 4 + (lane >> 4);
      int qcol = ((lane & 15) ^ (qrow & 15)) << 3;
      __builtin_amdgcn_global_load_lds((ga_u32*)(gq + (qrow * HDTOT + qcol) * 2),
                                       (lds_u32*)(lq + p * 1024), 16, 0, 0);
    }
  }
  __syncthreads();  // Q arrived; s_tj visible

  bf16x8 qf[2][4];  // Q B-frags: qrow = wq0 + qh*16 + l16
#pragma unroll
  for (int qh = 0; qh < 2; ++qh)
#pragma unroll
    for (int ks = 0; ks < 4; ++ks)
      qf[qh][ks] = ldsfrag(&bufK[0][0], wq0 + qh * 16 + l16, ks * 4 + quad);

  const int nv2 = 2 * s_nv;
  const char* kh = (const char*)(k + h * HD);
  const char* vh = (const char*)(vt + (size_t)(h * HD) * S_LEN);

  __syncthreads();  // all waves done reading Q before K0 DMA overwrites bufK[0]

  // issue half-tile 0 loads (drained at first loop barrier)
  {
    int key0 = s_tj[0] * 128;  // half 0
    const char* gk = kh + (size_t)key0 * (HDTOT * 2);
    const char* gv = vh + (size_t)key0 * 2;
    char* lk = (char*)bufK[0] + wave * 4096;
    char* lv = (char*)bufV[0] + wave * 4096;
#pragma unroll
    for (int p = 0; p < 4; ++p) {
      __builtin_amdgcn_global_load_lds((ga_u32*)(gk + offK[p]),
                                       (lds_u32*)(lk + p * 1024), 16, 0, 0);
      __builtin_amdgcn_global_load_lds((ga_u32*)(gv + offV[p]),
                                       (lds_u32*)(lv + p * 1024), 16, 0, 0);
    }
  }

  f32x4 oacc[2][8] = {};
  float m_st[2] = {-1e30f, -1e30f};
  float l_st[2] = {0.f, 0.f};

  for (int it = 0; it < nv2; ++it) {
    const int par = it & 1;
    const u16* K_c = bufK[par];
    const u16* V_c = bufV[par];
    const int tj = s_tj[it >> 1];
    const int half = it & 1;
    const bool diag = (tj == t);

    __syncthreads();  // drains half-tile-it loads; WAR-protects buffer 1-par

    // prefetch half-tile it+1 (in flight for the whole compute phase below)
    if (it + 1 < nv2) {
      int inx = it + 1;
      int key0 = s_tj[inx >> 1] * 128 + (inx & 1) * 64;
      const char* gk = kh + (size_t)key0 * (HDTOT * 2);
      const char* gv = vh + (size_t)key0 * 2;
      char* lk = (char*)bufK[1 - par] + wave * 4096;
      char* lv = (char*)bufV[1 - par] + wave * 4096;
#pragma unroll
      for (int p = 0; p < 4; ++p) {
        __builtin_amdgcn_global_load_lds((ga_u32*)(gk + offK[p]),
                                         (lds_u32*)(lk + p * 1024), 16, 0, 0);
        __builtin_amdgcn_global_load_lds((ga_u32*)(gv + offV[p]),
                                         (lds_u32*)(lv + p * 1024), 16, 0, 0);
      }
    }

    // S^T = K·Q^T : one kf read feeds both qh halves
    f32x4 sacc[2][4] = {};
    __builtin_amdgcn_s_setprio(1);
#pragma unroll
    for (int ks = 0; ks < 4; ++ks)
#pragma unroll
      for (int a = 0; a < 4; ++a) {
        bf16x8 kf = ldsfrag(K_c, a * 16 + l16, ks * 4 + quad);
        sacc[0][a] = mfma16(kf, qf[0][ks], sacc[0][a]);
        sacc[1][a] = mfma16(kf, qf[1][ks], sacc[1][a]);
      }
    __builtin_amdgcn_s_setprio(0);

    // online softmax per qh (tree reductions + exact defer-max)
    u32 pl[2][4], ph[2][4];
    float alpha[2];
    bool needR[2];
#pragma unroll
    for (int qh = 0; qh < 2; ++qh) {
      const int qr = wq0 + qh * 16 + l16;
      const int kb = half * 64;
      float amax[4];
#pragma unroll
      for (int a = 0; a < 4; ++a) {
        f32x4 s4 = sacc[qh][a];
#pragma unroll
        for (int r = 0; r < 4; ++r) {
          float sv = s4[r] * SM_SCALE;
          if (diag && (kb + a * 16 + quad * 4 + r > qr)) sv = -1e30f;
          s4[r] = sv;
        }
        sacc[qh][a] = s4;
        amax[a] = fmaxf(fmaxf(s4[0], s4[1]), fmaxf(s4[2], s4[3]));
      }
      float rmax = fmaxf(fmaxf(amax[0], amax[1]), fmaxf(amax[2], amax[3]));
      rmax = fmaxf(rmax, __shfl_xor(rmax, 16));
      rmax = fmaxf(rmax, __shfl_xor(rmax, 32));
      // exact defer-max: if no lane's max grew, alpha==1 for all -> skip rescale
      bool skip = __all(rmax <= m_st[qh]);
      float mnew = skip ? m_st[qh] : fmaxf(m_st[qh], rmax);
      alpha[qh] = skip ? 1.0f : __expf(m_st[qh] - mnew);
      needR[qh] = !skip;
      m_st[qh] = mnew;
      float rs0 = 0.f, rs1 = 0.f;
#pragma unroll
      for (int a = 0; a < 4; ++a) {
        f32x4 s4 = sacc[qh][a];
        float e0 = __expf(s4[0] - mnew);
        float e1 = __expf(s4[1] - mnew);
        float e2 = __expf(s4[2] - mnew);
        float e3 = __expf(s4[3] - mnew);
        rs0 += (e0 + e1);
        rs1 += (e2 + e3);
        pl[qh][a] = __builtin_amdgcn_perm(__builtin_bit_cast(u32, e1) + 0x8000u,
                                          __builtin_bit_cast(u32, e0) + 0x8000u,
                                          0x07060302u);
        ph[qh][a] = __builtin_amdgcn_perm(__builtin_bit_cast(u32, e3) + 0x8000u,
                                          __builtin_bit_cast(u32, e2) + 0x8000u,
                                          0x07060302u);
      }
      float rsum = rs0 + rs1;
      rsum += __shfl_xor(rsum, 16);
      rsum += __shfl_xor(rsum, 32);
      l_st[qh] = skip ? (l_st[qh] + rsum) : (l_st[qh] * alpha[qh] + rsum);
    }

    // rescale O only when needed (wave-uniform branch; alpha==1 otherwise)
#pragma unroll
    for (int qh = 0; qh < 2; ++qh) {
      if (needR[qh]) {
        f32x4 av;
#pragma unroll
        for (int r = 0; r < 4; ++r)
          av[r] = __shfl(alpha[qh], (lane & 48) | (quad * 4 + r));
#pragma unroll
        for (int nt = 0; nt < 8; ++nt) {
          f32x4 o4 = oacc[qh][nt];
          o4[0] *= av[0]; o4[1] *= av[1]; o4[2] *= av[2]; o4[3] *= av[3];
          oacc[qh][nt] = o4;
        }
      }
    }

    // O += P·V : A-frags via register shfl-transpose; one vf feeds both qh
    const int srcA = ((quad & 1) << 5) + l16;
    const int srcB = srcA + 16;
    const int hi = quad >> 1;
#pragma unroll
    for (int cc = 0; cc < 2; ++cc) {
      bf16x8 pa[2];
#pragma unroll
      for (int qh = 0; qh < 2; ++qh) {
        u32 x0 = __shfl(pl[qh][2 * cc], srcA), x1 = __shfl(ph[qh][2 * cc], srcA);
        u32 x2 = __shfl(pl[qh][2 * cc], srcB), x3 = __shfl(ph[qh][2 * cc], srcB);
        u32 y0 = __shfl(pl[qh][2 * cc + 1], srcA), y1 = __shfl(ph[qh][2 * cc + 1], srcA);
        u32 y2 = __shfl(pl[qh][2 * cc + 1], srcB), y3 = __shfl(ph[qh][2 * cc + 1], srcB);
        uint4 w;
        w.x = hi ? y0 : x0;
        w.y = hi ? y1 : x1;
        w.z = hi ? y2 : x2;
        w.w = hi ? y3 : x3;
        pa[qh] = __builtin_bit_cast(bf16x8, w);
      }
      __builtin_amdgcn_s_setprio(1);
#pragma unroll
      for (int nt = 0; nt < 8; ++nt) {
        bf16x8 vf = ldsfragV(V_c, nt * 16 + l16, cc * 4 + quad);
        oacc[0][nt] = mfma16(pa[0], vf, oacc[0][nt]);
        oacc[1][nt] = mfma16(pa[1], vf, oacc[1][nt]);
      }
      __builtin_amdgcn_s_setprio(0);
    }
  }

  // epilogue: normalize rows (1/l via shfl to O-row lanes) and store
#pragma unroll
  for (int qh = 0; qh < 2; ++qh) {
    float linv = 1.0f / l_st[qh];
    f32x4 iv;
#pragma unroll
    for (int r = 0; r < 4; ++r)
      iv[r] = __shfl(linv, (lane & 48) | (quad * 4 + r));
#pragma unroll
    for (int r = 0; r < 4; ++r) {
      size_t srow_o = (size_t)(t * 128 + wq0 + qh * 16 + quad * 4 + r);
#pragma unroll
      for (int nt = 0; nt < 8; ++nt)
        out[srow_o * HDTOT + h * HD + nt * 16 + l16] = f2bf(oacc[qh][nt][r] * iv[r]);
    }
  }
}

extern "C" void kernel_launch(void* const* d_in, const int* in_sizes, int n_in,
                              void* d_out, int out_size, void* d_ws, size_t ws_size,
                              hipStream_t stream) {
  const float* x   = (const float*)d_in[0];
  const float* wq  = (const float*)d_in[1];
  const float* wk  = (const float*)d_in[2];
  const float* wv  = (const float*)d_in[3];
  const float* wo  = (const float*)d_in[4];
  const float* ang = (const float*)d_in[5];
  const int* anch  = (const int*)d_in[6];

  char* ws = (char*)d_ws;
  const size_t SZ_SE = (size_t)S_LEN * HDTOT * sizeof(u16);  // 16 MB
  const size_t SZ_W  = (size_t)EMB * EMB * sizeof(u16);      // 8 MB
  u16* xb   = (u16*)(ws);
  u16* qb   = (u16*)(ws + SZ_SE);
  u16* kb   = (u16*)(ws + 2 * SZ_SE);
  u16* vb   = (u16*)(ws + 3 * SZ_SE);
  u16* vtb  = (u16*)(ws + 4 * SZ_SE);
  u16* attn = (u16*)(ws + 5 * SZ_SE);
  u16* wqT  = (u16*)(ws + 6 * SZ_SE);            // wqT,wkT,wvT contiguous ->
  u16* wkT  = (u16*)(ws + 6 * SZ_SE + SZ_W);     // single B^T for fused QKV
  u16* wvT  = (u16*)(ws + 6 * SZ_SE + 2 * SZ_W);
  u16* woT  = (u16*)(ws + 6 * SZ_SE + 3 * SZ_W);

  // cos/sin table lives in the first 2MB of d_out (overwritten by final gemm)
  float2* cssn = (float2*)d_out;

  k_prep<<<13312, 256, 0, stream>>>(x, xb, wq, wk, wv, wo, wqT, wkT, wvT, woT,
                                    ang, cssn);
  k_gemm256_qkv<<<dim3(24, 16), 512, 0, stream>>>(xb, wqT, qb, kb, vb, cssn);
  k_transpose_v<<<dim3(32, 64), 256, 0, stream>>>(vb, vtb);
  k_attn<<<dim3(512), 256, 0, stream>>>(qb, kb, vtb, anch, attn);
  k_gemm<false><<<dim3(16, 32), 256, 0, stream>>>(attn, woT, d_out, EMB, HDTOT);
}

// Round 9
// 374.665 us; speedup vs baseline: 1.1439x; 1.0259x over previous
//
#include <hip/hip_runtime.h>
#include <stdint.h>

typedef unsigned short u16;
typedef unsigned int u32;

#define S_LEN 4096
#define EMB 2048
#define NH 16
#define HD 128
#define HDTOT 2048
#define T_TILES 32
#define KANCH 8
#define SM_SCALE 0.088388347648318447f

typedef __bf16 bf16x8 __attribute__((ext_vector_type(8)));
typedef float f32x4 __attribute__((ext_vector_type(4)));

typedef const __attribute__((address_space(1))) u32 ga_u32;
typedef __attribute__((address_space(3))) u32 lds_u32;

__device__ __forceinline__ u16 f2bf(float f) {
  u32 b = __builtin_bit_cast(u32, f);
  b = (b + 0x7FFFu + ((b >> 16) & 1u)) >> 16;
  return (u16)b;
}
__device__ __forceinline__ float bf2f(u16 u) {
  return __builtin_bit_cast(float, ((u32)u) << 16);
}
__device__ __forceinline__ f32x4 mfma16(bf16x8 a, bf16x8 b, f32x4 c) {
  return __builtin_amdgcn_mfma_f32_16x16x32_bf16(a, b, c, 0, 0, 0);
}

#define ASM_LGKM0 do { asm volatile("s_waitcnt lgkmcnt(0)" ::: "memory"); \
                       __builtin_amdgcn_sched_barrier(0); } while (0)
#define ASM_VMC(n) do { asm volatile("s_waitcnt vmcnt(" #n ")" ::: "memory"); \
                        __builtin_amdgcn_sched_barrier(0); } while (0)

// ======= fused prep: convert_x (8192 blk) + transpose_w (4096) + sincos =====
__global__ __launch_bounds__(256) void k_prep(
    const float* __restrict__ x, u16* __restrict__ xb,
    const float* __restrict__ w0, const float* __restrict__ w1,
    const float* __restrict__ w2, const float* __restrict__ w3,
    u16* __restrict__ o0, u16* __restrict__ o1,
    u16* __restrict__ o2, u16* __restrict__ o3,
    const float* __restrict__ ang, float2* __restrict__ tab) {
  __shared__ float tile[64][68];
  const int bid = blockIdx.x;
  const int tid = threadIdx.x;
  if (bid < 8192) {
    int i = (bid * 256 + tid) * 4;
    float4 v = *(const float4*)(x + i);
    ushort4 o;
    o.x = f2bf(v.x); o.y = f2bf(v.y); o.z = f2bf(v.z); o.w = f2bf(v.w);
    *(ushort4*)(xb + i) = o;
  } else if (bid < 12288) {
    int idx = bid - 8192;
    int z = idx >> 10, rem = idx & 1023;
    int n0 = (rem & 31) * 64, k0 = (rem >> 5) * 64;
    const float* w; u16* o;
    if (z == 0)      { w = w0; o = o0; }
    else if (z == 1) { w = w1; o = o1; }
    else if (z == 2) { w = w2; o = o2; }
    else             { w = w3; o = o3; }
    int r = tid >> 4, cq = (tid & 15) << 2;
    for (int p = 0; p < 4; ++p) {
      float4 v = *(const float4*)(w + (size_t)(k0 + r + p * 16) * EMB + n0 + cq);
      tile[r + p * 16][cq + 0] = v.x;
      tile[r + p * 16][cq + 1] = v.y;
      tile[r + p * 16][cq + 2] = v.z;
      tile[r + p * 16][cq + 3] = v.w;
    }
    __syncthreads();
    for (int p = 0; p < 4; ++p) {
      int rn = r + p * 16;
      ushort4 u;
      u.x = f2bf(tile[cq + 0][rn]);
      u.y = f2bf(tile[cq + 1][rn]);
      u.z = f2bf(tile[cq + 2][rn]);
      u.w = f2bf(tile[cq + 3][rn]);
      *(ushort4*)(o + (size_t)(n0 + rn) * EMB + k0 + cq) = u;
    }
  } else {
    int i = (bid - 12288) * 256 + tid;
    float a = ang[i];
    float s, c;
    __sincosf(a, &s, &c);
    tab[i] = make_float2(c, s);
  }
}

// ------- v: [S][HDTOT] bf16 -> vT [HDTOT][S] bf16 -------
__global__ __launch_bounds__(256) void k_transpose_v(const u16* __restrict__ v,
                                                     u16* __restrict__ vt) {
  __shared__ u16 tile[64][72];
  int n0 = blockIdx.x * 64, s0 = blockIdx.y * 64;
  int tid = threadIdx.x;
  int r = tid >> 4, cq = (tid & 15) << 2;
  for (int p = 0; p < 4; ++p) {
    ushort4 u = *(const ushort4*)(v + (size_t)(s0 + r + p * 16) * HDTOT + n0 + cq);
    tile[r + p * 16][cq + 0] = u.x;
    tile[r + p * 16][cq + 1] = u.y;
    tile[r + p * 16][cq + 2] = u.z;
    tile[r + p * 16][cq + 3] = u.w;
  }
  __syncthreads();
  for (int p = 0; p < 4; ++p) {
    int rn = r + p * 16;
    ushort4 o;
    o.x = tile[cq + 0][rn];
    o.y = tile[cq + 1][rn];
    o.z = tile[cq + 2][rn];
    o.w = tile[cq + 3][rn];
    *(ushort4*)(vt + (size_t)(n0 + rn) * S_LEN + s0 + cq) = o;
  }
}

// ------- m97-style bf16 GEMM core (128x128 tile, BK=32) — out-proj ---------
template <bool BF16OUT>
__device__ __forceinline__ void gemm_body(const u16* __restrict__ A,
                                          const u16* __restrict__ Bt,
                                          void* __restrict__ Cv,
                                          int N, int K, int m0, int n0,
                                          u16* As, u16* Bs) {
  const int tid = threadIdx.x;
  const int lane = tid & 63, wave = tid >> 6;
  const int quad = lane >> 4, l16 = lane & 15;
  const int wm = (wave >> 1) * 64, wn = (wave & 1) * 64;
  const int sw = (quad ^ (l16 & 3) ^ ((l16 >> 2) & 3)) * 8;  // u16 units
  f32x4 acc[4][4] = {};

  const int flat0 = wave * 1024 + lane * 16;  // byte offset within 8KB tile
  for (int kt = 0; kt < K; kt += 32) {
    for (int half = 0; half < 2; ++half) {
      int flat = flat0 + half * 4096;
      int row = flat >> 6;
      int gl = (flat >> 4) & 3;
      int colb = ((gl ^ (row & 3) ^ ((row >> 2) & 3)) << 4);  // pre-swizzled src
      const char* ga = (const char*)A + ((size_t)(m0 + row) * K + kt) * 2 + colb;
      const char* gb = (const char*)Bt + ((size_t)(n0 + row) * K + kt) * 2 + colb;
      int loff = wave * 1024 + half * 4096;  // wave-uniform LDS byte offset
      __builtin_amdgcn_global_load_lds((ga_u32*)ga, (lds_u32*)((char*)As + loff), 16, 0, 0);
      __builtin_amdgcn_global_load_lds((ga_u32*)gb, (lds_u32*)((char*)Bs + loff), 16, 0, 0);
    }
    __syncthreads();
    bf16x8 af[4], bfr[4];
    for (int mt = 0; mt < 4; ++mt)
      af[mt] = *(const bf16x8*)(As + (wm + mt * 16 + l16) * 32 + sw);
    for (int nt = 0; nt < 4; ++nt)
      bfr[nt] = *(const bf16x8*)(Bs + (wn + nt * 16 + l16) * 32 + sw);
    for (int mt = 0; mt < 4; ++mt)
      for (int nt = 0; nt < 4; ++nt)
        acc[mt][nt] = mfma16(af[mt], bfr[nt], acc[mt][nt]);
    __syncthreads();
  }
  for (int mt = 0; mt < 4; ++mt) {
    int row = m0 + wm + mt * 16 + quad * 4;
    for (int nt = 0; nt < 4; ++nt) {
      int col = n0 + wn + nt * 16 + l16;
      for (int r = 0; r < 4; ++r) {
        if (BF16OUT)
          ((u16*)Cv)[(size_t)(row + r) * N + col] = f2bf(acc[mt][nt][r]);
        else
          ((float*)Cv)[(size_t)(row + r) * N + col] = acc[mt][nt][r];
      }
    }
  }
}

template <bool BF16OUT>
__global__ __launch_bounds__(256) void k_gemm(const u16* __restrict__ A,
                                              const u16* __restrict__ Bt,
                                              void* __restrict__ Cv,
                                              int N, int K) {
  __shared__ __align__(16) u16 As[128 * 32];
  __shared__ __align__(16) u16 Bs[128 * 32];
  gemm_body<BF16OUT>(A, Bt, Cv, N, K, blockIdx.y * 128, blockIdx.x * 128, As, Bs);
}

// ======= 128x256 BK=64 fused QKV GEMM — balanced 768-grid (3 blocks/CU) =====
// Fixes the measured structural imbalance (R3-R8: 384 blocks/256 CU -> 2
// rounds, half the CUs idle in round 2; OccupancyPercent 16 = 0.65 avg
// residency). 768 blocks = exactly 3 rounds on every CU. Keeps BK=64 /
// 128B-row swizzle (the only measured conflict-free layout: 0 conflicts
// R1-R3/R8 vs invariant 1.26e7 for 64B rows, R4/R5). LDS 96KB: A 2x16KB @0,
// B 2x32KB @32KB. 8 waves (2M x 4N), per-wave 64x64 out.
// Schedule: 3 phases/K-tile, R3-derived stage slots {ph1:(j+1).B1,
// ph2:(j+1).A, ph3:(j+2).B0}, end-of-iter vmcnt(2) — queue arithmetic:
// at end of iter j, outstanding = [(j+1).B0,(j+1).B1,(j+1).A,(j+2).B0];
// vmcnt(2) drains tile j+1 fully, keeps (j+2).B0 in flight (never 0).
// WAR: (j+2).B0 -> buf par, B0 rows last read ph1 (2 barriers earlier) OK.
__global__ __launch_bounds__(512, 1) void k_gemm_qkv(
    const u16* __restrict__ A, const u16* __restrict__ Bt,
    u16* __restrict__ q, u16* __restrict__ k, u16* __restrict__ v,
    const float2* __restrict__ cssn) {
  __shared__ __align__(16) u16 lds[49152];  // 96KB
  int orig = blockIdx.y * 24 + blockIdx.x;
  int flat = (orig & 7) * 96 + (orig >> 3);  // XCD-contiguous remap (768 = 8*96)
  const int bx = flat % 24, by = flat / 24;
  const int m0 = by * 128;
  const int n0g = bx * 256;                  // row into concatenated [wqT;wkT;wvT]
  u16* out = (bx < 8) ? q : ((bx < 16) ? k : v);
  const int ncol0 = (bx & 7) * 256;

  const int tid = threadIdx.x;
  const int lane = tid & 63, wave = tid >> 6;
  const int quad = lane >> 4, l16 = lane & 15;
  const int wm = wave >> 2, wn = wave & 3;   // 2M x 4N
  const int sw0 = (quad ^ (l16 & 7)) * 8, sw1 = ((quad ^ (l16 & 7)) ^ 4) * 8;

  // per-lane pre-swizzled global source offsets (LDS dest stays linear)
  u32 soff[4];
#pragma unroll
  for (int p = 0; p < 4; ++p) {
    int fl = p * 8192 + tid * 16;
    int row = fl >> 7;
    int gsw = ((fl >> 4) & 7) ^ (row & 7);
    soff[p] = (u32)row * 4096 + (u32)(gsw * 16);
  }
  const char* aBase = (const char*)A + (size_t)m0 * 4096;
  const char* bBase = (const char*)Bt + (size_t)n0g * 4096;
  const int dstW = wave * 1024;

  auto stA = [&](int buf, int kt) {  // A tile 128x64 = 16KB (rows 0..127)
#pragma unroll
    for (int p = 0; p < 2; ++p)
      __builtin_amdgcn_global_load_lds(
          (ga_u32*)(aBase + (size_t)kt * 128 + soff[p]),
          (lds_u32*)((char*)lds + buf * 16384 + p * 8192 + dstW), 16, 0, 0);
  };
  auto stB0 = [&](int buf, int kt) {  // B rows 0..127
#pragma unroll
    for (int p = 0; p < 2; ++p)
      __builtin_amdgcn_global_load_lds(
          (ga_u32*)(bBase + (size_t)kt * 128 + soff[p]),
          (lds_u32*)((char*)lds + 32768 + buf * 32768 + p * 8192 + dstW), 16, 0, 0);
  };
  auto stB1 = [&](int buf, int kt) {  // B rows 128..255
#pragma unroll
    for (int p = 2; p < 4; ++p)
      __builtin_amdgcn_global_load_lds(
          (ga_u32*)(bBase + (size_t)kt * 128 + soff[p]),
          (lds_u32*)((char*)lds + 32768 + buf * 32768 + p * 8192 + dstW), 16, 0, 0);
  };

  // read bases (u16 units); A row stride 64, B row = (wn*16+l16) + n*64
  const u16* aRd = lds + (wm * 64 + l16) * 64;
  const u16* bRd = lds + 16384 + (wn * 16 + l16) * 64;

  f32x4 acc[4][4] = {};

  // prologue: tile0 (6 loads) + tile1.B0 (2); drain tile0, keep 2 in flight
  stB0(0, 0); stB1(0, 0); stA(0, 0);
  stB0(1, 1);
  ASM_VMC(2);
  __builtin_amdgcn_s_barrier();

  const int NT = EMB / 64;  // 32
  for (int j = 0; j < NT; ++j) {
    const int par = j & 1;
    const u16* aT = aRd + par * 8192;
    const u16* bT = bRd + par * 16384;
    bf16x8 af[4][2], bfr[4][2];
    // ---- phase 1: read A m01 + B n01 (8 ds); stage (j+1).B1; MFMA m01xn01 --
#pragma unroll
    for (int m = 0; m < 2; ++m) {
      af[m][0] = *(const bf16x8*)(aT + m * 1024 + sw0);
      af[m][1] = *(const bf16x8*)(aT + m * 1024 + sw1);
    }
#pragma unroll
    for (int n = 0; n < 2; ++n) {
      bfr[n][0] = *(const bf16x8*)(bT + n * 4096 + sw0);
      bfr[n][1] = *(const bf16x8*)(bT + n * 4096 + sw1);
    }
    if (j + 1 < NT) stB1(1 - par, j + 1);
    __builtin_amdgcn_s_barrier();
    ASM_LGKM0;
    __builtin_amdgcn_s_setprio(1);
#pragma unroll
    for (int m = 0; m < 2; ++m)
#pragma unroll
      for (int n = 0; n < 2; ++n) {
        acc[m][n] = mfma16(af[m][0], bfr[n][0], acc[m][n]);
        acc[m][n] = mfma16(af[m][1], bfr[n][1], acc[m][n]);
      }
    __builtin_amdgcn_s_setprio(0);
    __builtin_amdgcn_s_barrier();
    // ---- phase 2: read B n23 (4 ds); stage (j+1).A; MFMA m01xn23 ----------
#pragma unroll
    for (int n = 2; n < 4; ++n) {
      bfr[n][0] = *(const bf16x8*)(bT + n * 4096 + sw0);
      bfr[n][1] = *(const bf16x8*)(bT + n * 4096 + sw1);
    }
    if (j + 1 < NT) stA(1 - par, j + 1);
    __builtin_amdgcn_s_barrier();
    ASM_LGKM0;
    __builtin_amdgcn_s_setprio(1);
#pragma unroll
    for (int m = 0; m < 2; ++m)
#pragma unroll
      for (int n = 2; n < 4; ++n) {
        acc[m][n] = mfma16(af[m][0], bfr[n][0], acc[m][n]);
        acc[m][n] = mfma16(af[m][1], bfr[n][1], acc[m][n]);
      }
    __builtin_amdgcn_s_setprio(0);
    __builtin_amdgcn_s_barrier();
    // ---- phase 3: read A m23 (4 ds); stage (j+2).B0; MFMA m23 x n0123 -----
#pragma unroll
    for (int m = 2; m < 4; ++m) {
      af[m][0] = *(const bf16x8*)(aT + m * 1024 + sw0);
      af[m][1] = *(const bf16x8*)(aT + m * 1024 + sw1);
    }
    if (j + 2 < NT) stB0(par, j + 2);
    __builtin_amdgcn_s_barrier();
    ASM_LGKM0;
    __builtin_amdgcn_s_setprio(1);
#pragma unroll
    for (int m = 2; m < 4; ++m)
#pragma unroll
      for (int n = 0; n < 4; ++n) {
        acc[m][n] = mfma16(af[m][0], bfr[n][0], acc[m][n]);
        acc[m][n] = mfma16(af[m][1], bfr[n][1], acc[m][n]);
      }
    __builtin_amdgcn_s_setprio(0);
    if (j < NT - 2) { ASM_VMC(2); }
    else if (j == NT - 2) { ASM_VMC(0); }
    if (j < NT - 1) __builtin_amdgcn_s_barrier();
  }

  // ---- epilogue ----
  if (bx < 16) {
    // q/k: register-local RoPE. d = wn*16+l16 (same angle col for both heads)
    const int dcol = wn * 16 + l16;
#pragma unroll
    for (int m = 0; m < 4; ++m) {
      int srow = m0 + wm * 64 + m * 16 + quad * 4;
#pragma unroll
      for (int r = 0; r < 4; ++r) {
        int s = srow + r;
        float2 cs2 = cssn[s * 64 + dcol];
        u16* op = out + (size_t)s * HDTOT + ncol0 + dcol;
        float lo0 = acc[m][0][r], hi0 = acc[m][1][r];
        op[0]   = f2bf(lo0 * cs2.x - hi0 * cs2.y);
        op[64]  = f2bf(hi0 * cs2.x + lo0 * cs2.y);
        float lo1 = acc[m][2][r], hi1 = acc[m][3][r];
        op[128] = f2bf(lo1 * cs2.x - hi1 * cs2.y);
        op[192] = f2bf(hi1 * cs2.x + lo1 * cs2.y);
      }
    }
  } else {
    // v: plain store (ntile = wn + 4n column mapping)
#pragma unroll
    for (int m = 0; m < 4; ++m) {
      int row = m0 + wm * 64 + m * 16 + quad * 4;
#pragma unroll
      for (int n = 0; n < 4; ++n) {
        int col = ncol0 + (wn + 4 * n) * 16 + l16;
#pragma unroll
        for (int r = 0; r < 4; ++r)
          out[(size_t)(row + r) * HDTOT + col] = f2bf(acc[m][n][r]);
      }
    }
  }
}

// ------- swizzled LDS fragment reads -------
__device__ __forceinline__ bf16x8 ldsfrag(const u16* __restrict__ sbuf, int r, int cb) {
  return *(const bf16x8*)(sbuf + r * 128 + (((cb ^ (r & 15)) << 3)));
}
__device__ __forceinline__ bf16x8 ldsfragV(const u16* __restrict__ sbuf, int r, int cb) {
  return *(const bf16x8*)(sbuf + r * 64 + (((cb ^ (r & 7)) << 3)));
}

// ------- block-sparse flash attention: one block per (t, h) ----------------
// R8 version unchanged (4 waves x 32 q-rows, exact defer-max, tree max).
__global__ __launch_bounds__(256, 2) void k_attn(const u16* __restrict__ q,
                                                 const u16* __restrict__ k,
                                                 const u16* __restrict__ vt,
                                                 const int* __restrict__ anch,
                                                 u16* __restrict__ out) {
  __shared__ __align__(16) u16 bufK[2][64 * 128];  // keys x dims (Q overlay at start)
  __shared__ __align__(16) u16 bufV[2][128 * 64];  // dims x keys
  __shared__ int s_tj[KANCH + 1];
  __shared__ int s_nv;
  const int i = blockIdx.x;
  const int p2 = (i ^ (i >> 8)) & 1;
  const int c = i >> 1;
  const int t = p2 ? (15 - (c >> 4)) : (16 + (c >> 4));
  const int h = c & 15;
  const int tid = threadIdx.x;
  const int lane = tid & 63, wave = tid >> 6;   // 4 waves
  const int quad = lane >> 4, l16 = lane & 15;
  const int wq0 = wave * 32;

  // K/V staging: 4 chunks/wave (K rows 0..63, V rows 0..127), swizzled cols
  int offK[4], offV[4];
#pragma unroll
  for (int p = 0; p < 4; ++p) {
    int krow = (wave * 4 + p) * 4 + (lane >> 4);
    int kcol = ((lane & 15) ^ (krow & 15)) << 3;
    offK[p] = (krow * HDTOT + kcol) * 2;
    int vrow = (wave * 4 + p) * 8 + (lane >> 3);
    int vcol = ((lane & 7) ^ (vrow & 7)) << 3;
    offV[p] = (vrow * S_LEN + vcol) * 2;
  }

  if (tid == 0) {
    int nv = 0;
    for (int j = 0; j < KANCH; ++j) {
      int tj = anch[((h * T_TILES) + t) * KANCH + j];
      if (tj <= t) s_tj[nv++] = tj;  // tj > t: fully future-masked, skip
    }
    s_tj[nv++] = t;  // local/diagonal tile
    s_nv = nv;
  }

  // stage full Q tile (128x128) into bufK[0]+bufK[1] (contiguous 32KB)
  {
    const char* gq = (const char*)(q + (size_t)(t * 128) * HDTOT + h * HD);
    char* lq = (char*)bufK + wave * 8192;
#pragma unroll
    for (int p = 0; p < 8; ++p) {
      int qrow = (wave * 8 + p) * 4 + (lane >> 4);
      int qcol = ((lane & 15) ^ (qrow & 15)) << 3;
      __builtin_amdgcn_global_load_lds((ga_u32*)(gq + (qrow * HDTOT + qcol) * 2),
                                       (lds_u32*)(lq + p * 1024), 16, 0, 0);
    }
  }
  __syncthreads();  // Q arrived; s_tj visible

  bf16x8 qf[2][4];  // Q B-frags: qrow = wq0 + qh*16 + l16
#pragma unroll
  for (int qh = 0; qh < 2; ++qh)
#pragma unroll
    for (int ks = 0; ks < 4; ++ks)
      qf[qh][ks] = ldsfrag(&bufK[0][0], wq0 + qh * 16 + l16, ks * 4 + quad);

  const int nv2 = 2 * s_nv;
  const char* kh = (const char*)(k + h * HD);
  const char* vh = (const char*)(vt + (size_t)(h * HD) * S_LEN);

  __syncthreads();  // all waves done reading Q before K0 DMA overwrites bufK[0]

  // issue half-tile 0 loads (drained at first loop barrier)
  {
    int key0 = s_tj[0] * 128;  // half 0
    const char* gk = kh + (size_t)key0 * (HDTOT * 2);
    const char* gv = vh + (size_t)key0 * 2;
    char* lk = (char*)bufK[0] + wave * 4096;
    char* lv = (char*)bufV[0] + wave * 4096;
#pragma unroll
    for (int p = 0; p < 4; ++p) {
      __builtin_amdgcn_global_load_lds((ga_u32*)(gk + offK[p]),
                                       (lds_u32*)(lk + p * 1024), 16, 0, 0);
      __builtin_amdgcn_global_load_lds((ga_u32*)(gv + offV[p]),
                                       (lds_u32*)(lv + p * 1024), 16, 0, 0);
    }
  }

  f32x4 oacc[2][8] = {};
  float m_st[2] = {-1e30f, -1e30f};
  float l_st[2] = {0.f, 0.f};

  for (int it = 0; it < nv2; ++it) {
    const int par = it & 1;
    const u16* K_c = bufK[par];
    const u16* V_c = bufV[par];
    const int tj = s_tj[it >> 1];
    const int half = it & 1;
    const bool diag = (tj == t);

    __syncthreads();  // drains half-tile-it loads; WAR-protects buffer 1-par

    // prefetch half-tile it+1 (in flight for the whole compute phase below)
    if (it + 1 < nv2) {
      int inx = it + 1;
      int key0 = s_tj[inx >> 1] * 128 + (inx & 1) * 64;
      const char* gk = kh + (size_t)key0 * (HDTOT * 2);
      const char* gv = vh + (size_t)key0 * 2;
      char* lk = (char*)bufK[1 - par] + wave * 4096;
      char* lv = (char*)bufV[1 - par] + wave * 4096;
#pragma unroll
      for (int p = 0; p < 4; ++p) {
        __builtin_amdgcn_global_load_lds((ga_u32*)(gk + offK[p]),
                                         (lds_u32*)(lk + p * 1024), 16, 0, 0);
        __builtin_amdgcn_global_load_lds((ga_u32*)(gv + offV[p]),
                                         (lds_u32*)(lv + p * 1024), 16, 0, 0);
      }
    }

    // S^T = K·Q^T : one kf read feeds both qh halves
    f32x4 sacc[2][4] = {};
    __builtin_amdgcn_s_setprio(1);
#pragma unroll
    for (int ks = 0; ks < 4; ++ks)
#pragma unroll
      for (int a = 0; a < 4; ++a) {
        bf16x8 kf = ldsfrag(K_c, a * 16 + l16, ks * 4 + quad);
        sacc[0][a] = mfma16(kf, qf[0][ks], sacc[0][a]);
        sacc[1][a] = mfma16(kf, qf[1][ks], sacc[1][a]);
      }
    __builtin_amdgcn_s_setprio(0);

    // online softmax per qh (tree reductions + exact defer-max)
    u32 pl[2][4], ph[2][4];
    float alpha[2];
    bool needR[2];
#pragma unroll
    for (int qh = 0; qh < 2; ++qh) {
      const int qr = wq0 + qh * 16 + l16;
      const int kb = half * 64;
      float amax[4];
#pragma unroll
      for (int a = 0; a < 4; ++a) {
        f32x4 s4 = sacc[qh][a];
#pragma unroll
        for (int r = 0; r < 4; ++r) {
          float sv = s4[r] * SM_SCALE;
          if (diag && (kb + a * 16 + quad * 4 + r > qr)) sv = -1e30f;
          s4[r] = sv;
        }
        sacc[qh][a] = s4;
        amax[a] = fmaxf(fmaxf(s4[0], s4[1]), fmaxf(s4[2], s4[3]));
      }
      float rmax = fmaxf(fmaxf(amax[0], amax[1]), fmaxf(amax[2], amax[3]));
      rmax = fmaxf(rmax, __shfl_xor(rmax, 16));
      rmax = fmaxf(rmax, __shfl_xor(rmax, 32));
      // exact defer-max: if no lane's max grew, alpha==1 for all -> skip rescale
      bool skip = __all(rmax <= m_st[qh]);
      float mnew = skip ? m_st[qh] : fmaxf(m_st[qh], rmax);
      alpha[qh] = skip ? 1.0f : __expf(m_st[qh] - mnew);
      needR[qh] = !skip;
      m_st[qh] = mnew;
      float rs0 = 0.f, rs1 = 0.f;
#pragma unroll
      for (int a = 0; a < 4; ++a) {
        f32x4 s4 = sacc[qh][a];
        float e0 = __expf(s4[0] - mnew);
        float e1 = __expf(s4[1] - mnew);
        float e2 = __expf(s4[2] - mnew);
        float e3 = __expf(s4[3] - mnew);
        rs0 += (e0 + e1);
        rs1 += (e2 + e3);
        pl[qh][a] = __builtin_amdgcn_perm(__builtin_bit_cast(u32, e1) + 0x8000u,
                                          __builtin_bit_cast(u32, e0) + 0x8000u,
                                          0x07060302u);
        ph[qh][a] = __builtin_amdgcn_perm(__builtin_bit_cast(u32, e3) + 0x8000u,
                                          __builtin_bit_cast(u32, e2) + 0x8000u,
                                          0x07060302u);
      }
      float rsum = rs0 + rs1;
      rsum += __shfl_xor(rsum, 16);
      rsum += __shfl_xor(rsum, 32);
      l_st[qh] = skip ? (l_st[qh] + rsum) : (l_st[qh] * alpha[qh] + rsum);
    }

    // rescale O only when needed (wave-uniform branch; alpha==1 otherwise)
#pragma unroll
    for (int qh = 0; qh < 2; ++qh) {
      if (needR[qh]) {
        f32x4 av;
#pragma unroll
        for (int r = 0; r < 4; ++r)
          av[r] = __shfl(alpha[qh], (lane & 48) | (quad * 4 + r));
#pragma unroll
        for (int nt = 0; nt < 8; ++nt) {
          f32x4 o4 = oacc[qh][nt];
          o4[0] *= av[0]; o4[1] *= av[1]; o4[2] *= av[2]; o4[3] *= av[3];
          oacc[qh][nt] = o4;
        }
      }
    }

    // O += P·V : A-frags via register shfl-transpose; one vf feeds both qh
    const int srcA = ((quad & 1) << 5) + l16;
    const int srcB = srcA + 16;
    const int hi = quad >> 1;
#pragma unroll
    for (int cc = 0; cc < 2; ++cc) {
      bf16x8 pa[2];
#pragma unroll
      for (int qh = 0; qh < 2; ++qh) {
        u32 x0 = __shfl(pl[qh][2 * cc], srcA), x1 = __shfl(ph[qh][2 * cc], srcA);
        u32 x2 = __shfl(pl[qh][2 * cc], srcB), x3 = __shfl(ph[qh][2 * cc], srcB);
        u32 y0 = __shfl(pl[qh][2 * cc + 1], srcA), y1 = __shfl(ph[qh][2 * cc + 1], srcA);
        u32 y2 = __shfl(pl[qh][2 * cc + 1], srcB), y3 = __shfl(ph[qh][2 * cc + 1], srcB);
        uint4 w;
        w.x = hi ? y0 : x0;
        w.y = hi ? y1 : x1;
        w.z = hi ? y2 : x2;
        w.w = hi ? y3 : x3;
        pa[qh] = __builtin_bit_cast(bf16x8, w);
      }
      __builtin_amdgcn_s_setprio(1);
#pragma unroll
      for (int nt = 0; nt < 8; ++nt) {
        bf16x8 vf = ldsfragV(V_c, nt * 16 + l16, cc * 4 + quad);
        oacc[0][nt] = mfma16(pa[0], vf, oacc[0][nt]);
        oacc[1][nt] = mfma16(pa[1], vf, oacc[1][nt]);
      }
      __builtin_amdgcn_s_setprio(0);
    }
  }

  // epilogue: normalize rows (1/l via shfl to O-row lanes) and store
#pragma unroll
  for (int qh = 0; qh < 2; ++qh) {
    float linv = 1.0f / l_st[qh];
    f32x4 iv;
#pragma unroll
    for (int r = 0; r < 4; ++r)
      iv[r] = __shfl(linv, (lane & 48) | (quad * 4 + r));
#pragma unroll
    for (int r = 0; r < 4; ++r) {
      size_t srow_o = (size_t)(t * 128 + wq0 + qh * 16 + quad * 4 + r);
#pragma unroll
      for (int nt = 0; nt < 8; ++nt)
        out[srow_o * HDTOT + h * HD + nt * 16 + l16] = f2bf(oacc[qh][nt][r] * iv[r]);
    }
  }
}

extern "C" void kernel_launch(void* const* d_in, const int* in_sizes, int n_in,
                              void* d_out, int out_size, void* d_ws, size_t ws_size,
                              hipStream_t stream) {
  const float* x   = (const float*)d_in[0];
  const float* wq  = (const float*)d_in[1];
  const float* wk  = (const float*)d_in[2];
  const float* wv  = (const float*)d_in[3];
  const float* wo  = (const float*)d_in[4];
  const float* ang = (const float*)d_in[5];
  const int* anch  = (const int*)d_in[6];

  char* ws = (char*)d_ws;
  const size_t SZ_SE = (size_t)S_LEN * HDTOT * sizeof(u16);  // 16 MB
  const size_t SZ_W  = (size_t)EMB * EMB * sizeof(u16);      // 8 MB
  u16* xb   = (u16*)(ws);
  u16* qb   = (u16*)(ws + SZ_SE);
  u16* kb   = (u16*)(ws + 2 * SZ_SE);
  u16* vb   = (u16*)(ws + 3 * SZ_SE);
  u16* vtb  = (u16*)(ws + 4 * SZ_SE);
  u16* attn = (u16*)(ws + 5 * SZ_SE);
  u16* wqT  = (u16*)(ws + 6 * SZ_SE);            // wqT,wkT,wvT contiguous ->
  u16* wkT  = (u16*)(ws + 6 * SZ_SE + SZ_W);     // single B^T for fused QKV
  u16* wvT  = (u16*)(ws + 6 * SZ_SE + 2 * SZ_W);
  u16* woT  = (u16*)(ws + 6 * SZ_SE + 3 * SZ_W);

  // cos/sin table lives in the first 2MB of d_out (overwritten by final gemm)
  float2* cssn = (float2*)d_out;

  k_prep<<<13312, 256, 0, stream>>>(x, xb, wq, wk, wv, wo, wqT, wkT, wvT, woT,
                                    ang, cssn);
  k_gemm_qkv<<<dim3(24, 32), 512, 0, stream>>>(xb, wqT, qb, kb, vb, cssn);
  k_transpose_v<<<dim3(32, 64), 256, 0, stream>>>(vb, vtb);
  k_attn<<<dim3(512), 256, 0, stream>>>(qb, kb, vtb, anch, attn);
  k_gemm<false><<<dim3(16, 32), 256, 0, stream>>>(attn, woT, d_out, EMB, HDTOT);
}